// Round 1
// baseline (401.829 us; speedup 1.0000x reference)
//
#include <hip/hip_runtime.h>
#include <hip/hip_bf16.h>
#include <stdint.h>

#define K_TOT 4096
#define N_TOT 11008
#define M_TOT 256
#define BM 128
#define BN 64
#define WST 72   // padded LDS row stride in ushorts (144B = 16B-aligned, 2-way-free banks)

using bf16x8 = __attribute__((ext_vector_type(8))) short;
using f32x4  = __attribute__((ext_vector_type(4))) float;

// ---------- prep: fp32 -> bf16 (RNE) for the activation ----------
__global__ void cvt_a_bf16(const float* __restrict__ in, uint32_t* __restrict__ out) {
    int i = blockIdx.x * blockDim.x + threadIdx.x;       // one float4 per thread
    const float4 v = ((const float4*)in)[i];
    uint32_t a = __float_as_uint(v.x), b = __float_as_uint(v.y),
             c = __float_as_uint(v.z), d = __float_as_uint(v.w);
    a += 0x7FFFu + ((a >> 16) & 1u);
    b += 0x7FFFu + ((b >> 16) & 1u);
    c += 0x7FFFu + ((c >> 16) & 1u);
    d += 0x7FFFu + ((d >> 16) & 1u);
    uint2 o;
    o.x = (a >> 16) | (b & 0xFFFF0000u);
    o.y = (c >> 16) | (d & 0xFFFF0000u);
    ((uint2*)out)[i] = o;
}

// ---------- dequant 16 fp32 -> 16 bf16 packed into 8 dwords ----------
__device__ __forceinline__ void dequant16(const float4 w[4], float rs, float zp, float sc,
                                          uint32_t o[8]) {
    float f[16];
#pragma unroll
    for (int j = 0; j < 4; ++j) {
        f[4 * j + 0] = w[j].x; f[4 * j + 1] = w[j].y;
        f[4 * j + 2] = w[j].z; f[4 * j + 3] = w[j].w;
    }
    uint32_t u[16];
#pragma unroll
    for (int i = 0; i < 16; ++i) {
        float q = rintf(f[i] * rs) + zp;          // round-half-even, matches jnp.round
        q = fminf(fmaxf(q, 0.0f), 15.0f);         // maxq = 15 (fixed by reference)
        float dq = (q - zp) * sc;
        uint32_t b = __float_as_uint(dq);
        u[i] = b + 0x7FFFu + ((b >> 16) & 1u);    // bf16 RNE in high 16 bits
    }
#pragma unroll
    for (int i = 0; i < 8; ++i)
        o[i] = (u[2 * i] >> 16) | (u[2 * i + 1] & 0xFFFF0000u);
}

__device__ __forceinline__ void compute_step(f32x4 acc[4][2], const uint16_t* const Ap[4],
                                             const uint16_t (*sw)[WST], int kt, int wn, int lane) {
    const int koff = kt * 64;
#pragma unroll
    for (int s = 0; s < 2; ++s) {
        bf16x8 a[4], b[2];
#pragma unroll
        for (int mi = 0; mi < 4; ++mi)
            a[mi] = *(const bf16x8*)(Ap[mi] + koff + s * 32);
#pragma unroll
        for (int ni = 0; ni < 2; ++ni)
            b[ni] = *(const bf16x8*)&sw[wn + ni * 16 + (lane & 15)][s * 32 + (lane >> 4) * 8];
#pragma unroll
        for (int mi = 0; mi < 4; ++mi)
#pragma unroll
            for (int ni = 0; ni < 2; ++ni)
                acc[mi][ni] = __builtin_amdgcn_mfma_f32_16x16x32_bf16(a[mi], b[ni], acc[mi][ni], 0, 0, 0);
    }
}

// ---------- fused dequant + GEMM ----------
__global__ __launch_bounds__(256, 2)
void wql_gemm(const uint16_t* __restrict__ A,      // bf16 [256][4096]
              const float* __restrict__ W,         // fp32 [11008][4096]
              const float* __restrict__ bias,
              const float* __restrict__ scale,
              const float* __restrict__ zero,
              float* __restrict__ O) {             // fp32 [256][11008]
    __shared__ uint16_t sW[2][BN][WST];            // 18.4 KB, double-buffered W tile (bf16)

    const int tid  = threadIdx.x;
    const int lane = tid & 63;
    const int wv   = tid >> 6;
    const int wm   = (wv & 1) * 64;
    const int wn   = (wv >> 1) * 32;
    const int m0   = blockIdx.x * BM;
    const int n0   = blockIdx.y * BN;

    // --- W staging role: thread owns one (row, 16-float k-segment) slot ---
    const int nloc = tid >> 2;                     // 0..63
    const int kseg = tid & 3;                      // 0..3
    const int wrow = n0 + nloc;
    const float* Wp = W + (size_t)wrow * K_TOT + kseg * 16;
    const float sc = scale[wrow];
    const float zp = zero[wrow];
    const float rs = 1.0f / sc;
    uint16_t* sdst0 = &sW[0][nloc][kseg * 16];
    uint16_t* sdst1 = &sW[1][nloc][kseg * 16];

    // --- A fragment base pointers (direct-from-global, L2-resident) ---
    const uint16_t* Ap[4];
#pragma unroll
    for (int mi = 0; mi < 4; ++mi)
        Ap[mi] = A + (size_t)(m0 + wm + mi * 16 + (lane & 15)) * K_TOT + (lane >> 4) * 8;

    f32x4 acc[4][2];
#pragma unroll
    for (int mi = 0; mi < 4; ++mi)
#pragma unroll
        for (int ni = 0; ni < 2; ++ni)
            acc[mi][ni] = (f32x4){0.f, 0.f, 0.f, 0.f};

    float4 bank0[4], bank1[4];

    // --- prologue: W(0) -> sW[0]; W(1) -> bank1 ---
#pragma unroll
    for (int j = 0; j < 4; ++j) bank0[j] = ((const float4*)Wp)[j];
    {
        uint32_t o[8];
        dequant16(bank0, rs, zp, sc, o);
        ((uint4*)sdst0)[0] = make_uint4(o[0], o[1], o[2], o[3]);
        ((uint4*)sdst0)[1] = make_uint4(o[4], o[5], o[6], o[7]);
    }
#pragma unroll
    for (int j = 0; j < 4; ++j) bank1[j] = ((const float4*)(Wp + 64))[j];
    __syncthreads();

    for (int kt = 0; kt < K_TOT / 64; kt += 2) {
        // ---- even iter: compute sW[0]; dequant bank1 -> sW[1]; load kt+2 -> bank0 ----
        if (kt + 2 < 64) {
            const float4* p = (const float4*)(Wp + (size_t)(kt + 2) * 64);
#pragma unroll
            for (int j = 0; j < 4; ++j) bank0[j] = p[j];
        }
        compute_step(acc, Ap, sW[0], kt, wn, lane);
        {
            uint32_t o[8];
            dequant16(bank1, rs, zp, sc, o);
            ((uint4*)sdst1)[0] = make_uint4(o[0], o[1], o[2], o[3]);
            ((uint4*)sdst1)[1] = make_uint4(o[4], o[5], o[6], o[7]);
        }
        __syncthreads();

        // ---- odd iter: compute sW[1]; dequant bank0 -> sW[0]; load kt+3 -> bank1 ----
        if (kt + 3 < 64) {
            const float4* p = (const float4*)(Wp + (size_t)(kt + 3) * 64);
#pragma unroll
            for (int j = 0; j < 4; ++j) bank1[j] = p[j];
        }
        compute_step(acc, Ap, sW[1], kt + 1, wn, lane);
        if (kt + 2 < 64) {
            uint32_t o[8];
            dequant16(bank0, rs, zp, sc, o);
            ((uint4*)sdst0)[0] = make_uint4(o[0], o[1], o[2], o[3]);
            ((uint4*)sdst0)[1] = make_uint4(o[4], o[5], o[6], o[7]);
        }
        __syncthreads();
    }

    // --- epilogue: bias add + store (fp32) ---
    const int colbase = n0 + wn + (lane & 15);
    const float bv0 = bias[colbase];
    const float bv1 = bias[colbase + 16];
    const int rbase = m0 + wm + ((lane >> 4) << 2);
#pragma unroll
    for (int mi = 0; mi < 4; ++mi) {
#pragma unroll
        for (int ni = 0; ni < 2; ++ni) {
            const float bv = ni ? bv1 : bv0;
            const int col = colbase + ni * 16;
#pragma unroll
            for (int r = 0; r < 4; ++r) {
                const int row = rbase + mi * 16 + r;
                O[(size_t)row * N_TOT + col] = acc[mi][ni][r] + bv;
            }
        }
    }
}

extern "C" void kernel_launch(void* const* d_in, const int* in_sizes, int n_in,
                              void* d_out, int out_size, void* d_ws, size_t ws_size,
                              hipStream_t stream) {
    const float* inp    = (const float*)d_in[0];
    const float* weight = (const float*)d_in[1];
    const float* bias   = (const float*)d_in[2];
    const float* scale  = (const float*)d_in[3];
    const float* zero   = (const float*)d_in[4];
    // d_in[5] = maxq scalar; fixed at 15 by the reference, hardcoded in dequant16.

    uint32_t* Abf = (uint32_t*)d_ws;               // 2 MB bf16 activation

    cvt_a_bf16<<<dim3((M_TOT * K_TOT / 4) / 256), dim3(256), 0, stream>>>(inp, Abf);

    dim3 grid(M_TOT / BM, N_TOT / BN);             // (2, 172) = 344 blocks
    wql_gemm<<<grid, dim3(256), 0, stream>>>((const uint16_t*)Abf, weight, bias, scale, zero,
                                             (float*)d_out);
}

// Round 2
// 368.786 us; speedup vs baseline: 1.0896x; 1.0896x over previous
//
#include <hip/hip_runtime.h>
#include <hip/hip_bf16.h>
#include <stdint.h>

#define K_TOT 4096
#define N_TOT 11008
#define M_TOT 256
#define BM 128
#define BN 64
#define WST 72   // padded LDS row stride in ushorts (144B = 16B-aligned, 2-way-free banks)

using bf16x8 = __attribute__((ext_vector_type(8))) short;
using f32x4  = __attribute__((ext_vector_type(4))) float;

// ---------- prep: fp32 -> bf16 (RNE) for the activation ----------
__global__ void cvt_a_bf16(const float* __restrict__ in, uint32_t* __restrict__ out) {
    int i = blockIdx.x * blockDim.x + threadIdx.x;       // one float4 per thread
    const float4 v = ((const float4*)in)[i];
    uint32_t a = __float_as_uint(v.x), b = __float_as_uint(v.y),
             c = __float_as_uint(v.z), d = __float_as_uint(v.w);
    a += 0x7FFFu + ((a >> 16) & 1u);
    b += 0x7FFFu + ((b >> 16) & 1u);
    c += 0x7FFFu + ((c >> 16) & 1u);
    d += 0x7FFFu + ((d >> 16) & 1u);
    uint2 o;
    o.x = (a >> 16) | (b & 0xFFFF0000u);
    o.y = (c >> 16) | (d & 0xFFFF0000u);
    ((uint2*)out)[i] = o;
}

// ---------- dequant 16 fp32 -> 16 bf16 packed into 8 dwords ----------
__device__ __forceinline__ void dequant16(const float4 w[4], float rs, float zp, float sc,
                                          uint32_t o[8]) {
    float f[16];
#pragma unroll
    for (int j = 0; j < 4; ++j) {
        f[4 * j + 0] = w[j].x; f[4 * j + 1] = w[j].y;
        f[4 * j + 2] = w[j].z; f[4 * j + 3] = w[j].w;
    }
    uint32_t u[16];
#pragma unroll
    for (int i = 0; i < 16; ++i) {
        float q = rintf(f[i] * rs) + zp;          // round-half-even, matches jnp.round
        q = fminf(fmaxf(q, 0.0f), 15.0f);         // maxq = 15 (fixed by reference)
        float dq = (q - zp) * sc;
        uint32_t b = __float_as_uint(dq);
        u[i] = b + 0x7FFFu + ((b >> 16) & 1u);    // bf16 RNE in high 16 bits
    }
#pragma unroll
    for (int i = 0; i < 8; ++i)
        o[i] = (u[2 * i] >> 16) | (u[2 * i + 1] & 0xFFFF0000u);
}

__device__ __forceinline__ void compute_step(f32x4 acc[4][2], const uint16_t* const Ap[4],
                                             const uint16_t (*sw)[WST], int kt, int wn, int lane) {
    const int koff = kt * 64;
#pragma unroll
    for (int s = 0; s < 2; ++s) {
        bf16x8 a[4], b[2];
#pragma unroll
        for (int mi = 0; mi < 4; ++mi)
            a[mi] = *(const bf16x8*)(Ap[mi] + koff + s * 32);
#pragma unroll
        for (int ni = 0; ni < 2; ++ni)
            b[ni] = *(const bf16x8*)&sw[wn + ni * 16 + (lane & 15)][s * 32 + (lane >> 4) * 8];
#pragma unroll
        for (int mi = 0; mi < 4; ++mi)
#pragma unroll
            for (int ni = 0; ni < 2; ++ni)
                acc[mi][ni] = __builtin_amdgcn_mfma_f32_16x16x32_bf16(a[mi], b[ni], acc[mi][ni], 0, 0, 0);
    }
}

// ---------- fused dequant + GEMM over a K-chunk, writes fp32 partials ----------
__global__ __launch_bounds__(256, 4)
void wql_gemm(const uint16_t* __restrict__ A,      // bf16 [256][4096]
              const float* __restrict__ W,         // fp32 [11008][4096]
              const float* __restrict__ scale,
              const float* __restrict__ zero,
              float* __restrict__ P,               // fp32 [KS][256][11008]
              int kloc) {                          // K-chunk length (multiple of 128)
    __shared__ uint16_t sW[2][BN][WST];            // 18.4 KB, double-buffered W tile (bf16)

    const int tid  = threadIdx.x;
    const int lane = tid & 63;
    const int wv   = tid >> 6;
    const int wm   = (wv & 1) * 64;
    const int wn   = (wv >> 1) * 32;
    const int m0   = blockIdx.x * BM;
    const int n0   = blockIdx.y * BN;
    const int k0   = blockIdx.z * kloc;
    const int nkt  = kloc / 64;

    // --- W staging role: thread owns one (row, 16-float k-segment) slot ---
    const int nloc = tid >> 2;                     // 0..63
    const int kseg = tid & 3;                      // 0..3
    const int wrow = n0 + nloc;
    const float* Wp = W + (size_t)wrow * K_TOT + k0 + kseg * 16;
    const float sc = scale[wrow];
    const float zp = zero[wrow];
    const float rs = 1.0f / sc;
    uint16_t* sdst0 = &sW[0][nloc][kseg * 16];
    uint16_t* sdst1 = &sW[1][nloc][kseg * 16];

    // --- A fragment base pointers (direct-from-global, L2/LLC-resident) ---
    const uint16_t* Ap[4];
#pragma unroll
    for (int mi = 0; mi < 4; ++mi)
        Ap[mi] = A + (size_t)(m0 + wm + mi * 16 + (lane & 15)) * K_TOT + k0 + (lane >> 4) * 8;

    f32x4 acc[4][2];
#pragma unroll
    for (int mi = 0; mi < 4; ++mi)
#pragma unroll
        for (int ni = 0; ni < 2; ++ni)
            acc[mi][ni] = (f32x4){0.f, 0.f, 0.f, 0.f};

    float4 bank0[4], bank1[4];

    // --- prologue: W(0) -> sW[0]; W(1) -> bank1 ---
#pragma unroll
    for (int j = 0; j < 4; ++j) bank0[j] = ((const float4*)Wp)[j];
    {
        uint32_t o[8];
        dequant16(bank0, rs, zp, sc, o);
        ((uint4*)sdst0)[0] = make_uint4(o[0], o[1], o[2], o[3]);
        ((uint4*)sdst0)[1] = make_uint4(o[4], o[5], o[6], o[7]);
    }
#pragma unroll
    for (int j = 0; j < 4; ++j) bank1[j] = ((const float4*)(Wp + 64))[j];
    __syncthreads();

    for (int kt = 0; kt < nkt; kt += 2) {
        // ---- even iter: compute sW[0]; dequant bank1 -> sW[1]; load kt+2 -> bank0 ----
        if (kt + 2 < nkt) {
            const float4* p = (const float4*)(Wp + (size_t)(kt + 2) * 64);
#pragma unroll
            for (int j = 0; j < 4; ++j) bank0[j] = p[j];
        }
        compute_step(acc, Ap, sW[0], kt, wn, lane);
        {
            uint32_t o[8];
            dequant16(bank1, rs, zp, sc, o);
            ((uint4*)sdst1)[0] = make_uint4(o[0], o[1], o[2], o[3]);
            ((uint4*)sdst1)[1] = make_uint4(o[4], o[5], o[6], o[7]);
        }
        __syncthreads();

        // ---- odd iter: compute sW[1]; dequant bank0 -> sW[0]; load kt+3 -> bank1 ----
        if (kt + 3 < nkt) {
            const float4* p = (const float4*)(Wp + (size_t)(kt + 3) * 64);
#pragma unroll
            for (int j = 0; j < 4; ++j) bank1[j] = p[j];
        }
        compute_step(acc, Ap, sW[1], kt + 1, wn, lane);
        if (kt + 2 < nkt) {
            uint32_t o[8];
            dequant16(bank0, rs, zp, sc, o);
            ((uint4*)sdst0)[0] = make_uint4(o[0], o[1], o[2], o[3]);
            ((uint4*)sdst0)[1] = make_uint4(o[4], o[5], o[6], o[7]);
        }
        __syncthreads();
    }

    // --- epilogue: store fp32 partial (no bias here) ---
    float* Pb = P + (size_t)blockIdx.z * M_TOT * N_TOT;
    const int colbase = n0 + wn + (lane & 15);
    const int rbase = m0 + wm + ((lane >> 4) << 2);
#pragma unroll
    for (int mi = 0; mi < 4; ++mi) {
#pragma unroll
        for (int ni = 0; ni < 2; ++ni) {
            const int col = colbase + ni * 16;
#pragma unroll
            for (int r = 0; r < 4; ++r) {
                const int row = rbase + mi * 16 + r;
                Pb[(size_t)row * N_TOT + col] = acc[mi][ni][r];
            }
        }
    }
}

// ---------- reduce KS partial slices + bias -> out (float4 per thread) ----------
__global__ void reduce_bias(const float* __restrict__ P, const float* __restrict__ bias,
                            float* __restrict__ out, int ks) {
    const int i4 = blockIdx.x * blockDim.x + threadIdx.x;   // float4 index
    const size_t tot4 = (size_t)M_TOT * N_TOT / 4;
    const int col = (int)(((size_t)i4 * 4) % N_TOT);        // rows are multiple-of-4 long
    float4 acc = ((const float4*)P)[i4];
    for (int s = 1; s < ks; ++s) {
        const float4 v = ((const float4*)P)[(size_t)s * tot4 + i4];
        acc.x += v.x; acc.y += v.y; acc.z += v.z; acc.w += v.w;
    }
    const float4 b = *(const float4*)(bias + col);
    acc.x += b.x; acc.y += b.y; acc.z += b.z; acc.w += b.w;
    ((float4*)out)[i4] = acc;
}

extern "C" void kernel_launch(void* const* d_in, const int* in_sizes, int n_in,
                              void* d_out, int out_size, void* d_ws, size_t ws_size,
                              hipStream_t stream) {
    const float* inp    = (const float*)d_in[0];
    const float* weight = (const float*)d_in[1];
    const float* bias   = (const float*)d_in[2];
    const float* scale  = (const float*)d_in[3];
    const float* zero   = (const float*)d_in[4];
    // d_in[5] = maxq scalar; fixed at 15 by the reference, hardcoded in dequant16.

    const size_t A_BYTES = (size_t)M_TOT * K_TOT * 2;       // 2 MB bf16 activation
    const size_t SLICE   = (size_t)M_TOT * N_TOT * 4;       // 11 MB fp32 partial

    uint32_t* Abf = (uint32_t*)d_ws;
    float* partial;
    int KS;
    if (ws_size >= A_BYTES + 4 * SLICE) { KS = 4; partial = (float*)((char*)d_ws + A_BYTES); }
    else if (ws_size >= A_BYTES + 2 * SLICE) { KS = 2; partial = (float*)((char*)d_ws + A_BYTES); }
    else { KS = 1; partial = (float*)d_out; }               // in-place: reduce adds bias only

    cvt_a_bf16<<<dim3((M_TOT * K_TOT / 4) / 256), dim3(256), 0, stream>>>(inp, Abf);

    dim3 grid(M_TOT / BM, N_TOT / BN, KS);                  // (2, 172, KS)
    wql_gemm<<<grid, dim3(256), 0, stream>>>((const uint16_t*)Abf, weight, scale, zero,
                                             partial, K_TOT / KS);

    reduce_bias<<<dim3((M_TOT * N_TOT / 4) / 256), dim3(256), 0, stream>>>(
        partial, bias, (float*)d_out, KS);
}